// Round 12
// baseline (258.605 us; speedup 1.0000x reference)
//
#include <hip/hip_runtime.h>
#include <hip/hip_bf16.h>

// STU forward. R12 = R11 + paired-barrier K-loop & per-XCD split ownership:
//  - gemm_d/gemm_r: 128x128 tiles, dbuf-of-PAIRS (4 stages x 16 KB = 64 KB),
//    ONE vmcnt(0)+s_barrier per 64-K (half of R7/R11's barrier count).
//  - SPLITD=8: 512 main blocks (2/CU uniform); XCD id%8 owns exactly one
//    K-split -> B chunk 2.24 MB L2-resident; A col-quads adjacent on one XCD.
//  - gemm_d / gemm_r split into separate kernels (profiler visibility).
// conv/preps/ztaps/reduce unchanged from R11. NTAP=6, bf16 split-K partials,
// fused Phi chain, 6 launches, XOR swizzle (0 bank conflicts).

using bf16 = __hip_bfloat16;
typedef __attribute__((ext_vector_type(8))) short bf16x8;
typedef __attribute__((ext_vector_type(4))) float f32x4;

#define B_   2
#define L_   1024
#define D_   512
#define K_   16
#define KT   17920      // 32*512 (conv channels) + 3*512 (M_u taps)
#define ROWS 2048       // B*L
#define NTAP 6          // AR taps s=1..6 (s=0 identity in fp32)
#define PBLD 3584       // PB row stride: 7 slots (s=0..6) * 512
#define SPLITD 8        // one K-split per XCD
#define SPLITR 6        // one tap per split, K=512
#define ZBROWS 1032     // 8 guard rows + 1024 per batch

// s_waitcnt imm: [3:0] vmcnt lo, [6:4] expcnt, [11:8] lgkmcnt, [15:14] vmcnt hi
#define WAIT_VM4 0x0F74   // vmcnt<=4 (conv single-stage = 4 loads/wave)
#define WAIT_VM0 0x0F70

__device__ __forceinline__ void gll16(const void* g, void* l) {
    __builtin_amdgcn_global_load_lds(
        (const __attribute__((address_space(1))) unsigned int*)g,
        (__attribute__((address_space(3))) unsigned int*)l, 16, 0, 0);
}

// ---------------- prep: ALL prep work in one launch ----------------
__global__ void prep_all(const float* __restrict__ u, const float* __restrict__ fil,
                         const float* __restrict__ Mu, const float* __restrict__ My,
                         const float* __restrict__ Mp, const float* __restrict__ Mm,
                         bf16* __restrict__ U, bf16* __restrict__ BT,
                         bf16* __restrict__ PB, bf16* __restrict__ W,
                         bf16* __restrict__ Myb, bf16* __restrict__ BTT,
                         bf16* __restrict__ uPT) {
    __shared__ bf16 t[64][72];
    int bid = blockIdx.x, tid = threadIdx.x;
    auto pack4 = [](float4 v) {
        ushort4 o; bf16 h;
        h = __float2bfloat16(v.x); o.x = *(unsigned short*)&h;
        h = __float2bfloat16(v.y); o.y = *(unsigned short*)&h;
        h = __float2bfloat16(v.z); o.z = *(unsigned short*)&h;
        h = __float2bfloat16(v.w); o.w = *(unsigned short*)&h;
        return o;
    };
    if (bid < 3072) {                        // U taps
        int e4 = bid * 256 + tid;
        int r = e4 / 384, rem = e4 % 384;
        int tt = rem >> 7, f = (rem & 127) * 4;
        int b = r >> 10, l = r & 1023;
        float4 v = {0.f, 0.f, 0.f, 0.f};
        if (l >= tt) v = *(const float4*)&u[((size_t)b * L_ + l - tt) * D_ + f];
        *(ushort4*)&U[(size_t)r * KT + 16384 + tt * 512 + f] = pack4(v);
    } else if (bid < 3840) {                 // BT taps
        int e4 = (bid - 3072) * 256 + tid;
        int o = e4 / 384, tf4 = (e4 % 384) * 4;
        float4 v = *(const float4*)&Mu[(size_t)o * 1536 + tf4];
        *(ushort4*)&BT[(size_t)o * KT + 16384 + tf4] = pack4(v);
    } else if (bid < 4352) {                 // PB: P0=I, P1=M_y[:,0,:]
        int e4 = (bid - 3840) * 256 + tid;
        int n = e4 >> 8, c4 = (e4 & 255) * 4;
        float4 v;
        if (c4 < 512) {
            v.x = (n == c4) ? 1.f : 0.f;     v.y = (n == c4 + 1) ? 1.f : 0.f;
            v.z = (n == c4 + 2) ? 1.f : 0.f; v.w = (n == c4 + 3) ? 1.f : 0.f;
        } else v = *(const float4*)&My[(size_t)n * 1024 + (c4 - 512)];
        *(ushort4*)&PB[(size_t)n * PBLD + c4] = pack4(v);
    } else if (bid < 5120) {                 // Toeplitz W tiles (3 sets), pre-swizzled
        int tile = bid - 4352;
        int set = tile >> 8, rem = tile & 255;
        int k = rem >> 4, g = (rem >> 2) & 3, kb = rem & 3;
        for (int idx = tid; idx < 4096; idx += 256) {
            int i = idx >> 5, jp = idx & 31;
            int j = ((jp >> 3) ^ ((i >> 1) & 3)) * 8 + (jp & 7);
            int x = g * 128 + i - kb * 32 - j - (set == 2 ? 1 : 0);
            float v = 0.f;
            if (x >= 0) {
                int row = (set == 0) ? 2 * x : 2 * x + 1;
                v = fil[row * K_ + k];
            }
            W[(size_t)tile * 4096 + idx] = __float2bfloat16(v);
        }
    } else if (bid < 5632) {                 // Myb = bf16(My)
        int e4 = (bid - 5120) * 256 + tid;
        float4 v = *(const float4*)&My[(size_t)e4 * 4];
        *(ushort4*)&Myb[(size_t)e4 * 4] = pack4(v);
    } else {                                 // ---- transpose sections ----
        int tt = bid - 5632;                 // 2240 = 35 z * 64 (x,y)
        int zb = tt >> 6, rem = tt & 63;
        int bx = rem & 7, by = rem >> 3;
        int col = tid & 63, r0 = (tid >> 6) * 16;
        if (zb < 32) {                       // BT[o][c*512+d] = (Mp +/- Mm)[k][d][o]
            int dt = bx * 64, ot = by * 64, c = zb;
            int k = c & 15;
            const float* sp = Mp + (size_t)k * D_ * D_;
            const float* sm = Mm + (size_t)k * D_ * D_;
            float sg = (c < 16) ? 1.f : -1.f;
            for (int i = 0; i < 16; ++i) {
                size_t o_ = (size_t)(dt + r0 + i) * D_ + ot + col;
                t[r0 + i][col] = __float2bfloat16(sp[o_] + sg * sm[o_]);
            }
            __syncthreads();
            for (int i = 0; i < 16; ++i)
                BT[(size_t)(ot + r0 + i) * KT + c * D_ + dt + col] = t[col][r0 + i];
        } else if (zb < 34) {                // BTT[f][h*512+d] = M_y[d][1-h][f]
            int h = zb - 32;
            int dt = bx * 64, ft = by * 64;
            for (int i = 0; i < 16; ++i)
                t[r0 + i][col] = __float2bfloat16(My[(size_t)(dt + r0 + i) * 1024 + (1 - h) * 512 + ft + col]);
            __syncthreads();
            for (int i = 0; i < 16; ++i)
                BTT[(size_t)(ft + r0 + i) * 1024 + h * 512 + dt + col] = t[col][r0 + i];
        } else {                             // uPT[b][p][d][m'] = u[b][2m'+p][d]
            for (int it = 0; it < 4; ++it) {
                int b = it >> 1, p = it & 1;
                int mt = bx * 64, dt = by * 64;
                __syncthreads();
                for (int i = 0; i < 16; ++i)
                    t[r0 + i][col] = __float2bfloat16(u[((size_t)b * L_ + 2 * (mt + r0 + i) + p) * D_ + dt + col]);
                __syncthreads();
                for (int i = 0; i < 16; ++i)
                    uPT[((size_t)it * 512 + dt + r0 + i) * 512 + mt + col] = t[col][r0 + i];
            }
        }
    }
}

// ---- shared body for small bf16-out GEMMs (caller LDS, __syncthreads ok) ----
__device__ __forceinline__ void phi_body(
    const bf16* A, int lda, const bf16* BT, int ldb,
    bf16* out, int ldo, int klen, const bf16* add, int lad,
    int row0, int col0, bf16* sA, bf16* sB)
{
    const int tid = threadIdx.x, lane = tid & 63, wave = tid >> 6;
    const int wm = (wave & 1) * 64, wn = (wave >> 1) * 64;
    const int ml = lane & 15, q = lane >> 4;
    const int srow = lane >> 2, scol = (((lane & 3) ^ ((srow >> 1) & 3))) * 8;
    const int swz = ((ml >> 1) & 3);
    f32x4 acc[4][4] = {};

    for (int k = 0; k < klen; k += 32) {
        __syncthreads();
        #pragma unroll
        for (int repi = 0; repi < 2; ++repi) {
            int a = wave + repi * 4;
            gll16(A  + (size_t)(row0 + a * 16 + srow) * lda + k + scol, &sA[a * 512]);
            gll16(BT + (size_t)(col0 + a * 16 + srow) * ldb + k + scol, &sB[a * 512]);
        }
        __syncthreads();
        bf16x8 af[4], bfr[4];
        #pragma unroll
        for (int i = 0; i < 4; ++i)
            af[i] = *(const bf16x8*)&sA[(wm + i * 16 + ml) * 32 + (q ^ swz) * 8];
        #pragma unroll
        for (int j = 0; j < 4; ++j)
            bfr[j] = *(const bf16x8*)&sB[(wn + j * 16 + ml) * 32 + (q ^ swz) * 8];
        #pragma unroll
        for (int i = 0; i < 4; ++i)
            #pragma unroll
            for (int j = 0; j < 4; ++j)
                acc[i][j] = __builtin_amdgcn_mfma_f32_16x16x32_bf16(af[i], bfr[j], acc[i][j], 0, 0, 0);
    }
    #pragma unroll
    for (int i = 0; i < 4; ++i)
        #pragma unroll
        for (int j = 0; j < 4; ++j)
            #pragma unroll
            for (int reg = 0; reg < 4; ++reg) {
                int r = row0 + wm + i * 16 + q * 4 + reg;
                int cc = col0 + wn + j * 16 + ml;
                float v = acc[i][j][reg];
                if (add) v += __bfloat162float(add[(size_t)r * lad + cc]);
                out[(size_t)r * ldo + cc] = __float2bfloat16(v);
            }
}

// sum 8 bf16 Stage-D partials -> z (fp32) + guard-padded bf16 copy zb
// bid<32: fused Phi doubling2 [P5|P6] = [P3|P4] x BTT (dispatched first)
// bid==32: zero the guard rows of zb
__global__ void k_ztaps(const bf16* __restrict__ partD, float* __restrict__ z,
                        bf16* __restrict__ zbuf, bf16* PB, const bf16* BTT) {
    __shared__ bf16 sA[4096];
    __shared__ bf16 sB[4096];
    int bid = blockIdx.x;
    if (bid < 32) {
        int row0 = (bid & 3) * 128, col0 = (bid >> 2) * 128;   // 4 x 8 tiles: 512x1024
        phi_body(PB + 3 * 512, PBLD, BTT, 1024, PB + 5 * 512, PBLD, 1024,
                 nullptr, 0, row0, col0, sA, sB);
        return;
    }
    if (bid == 32) {                         // zero 2x8 guard rows
        ushort4 z4 = {0, 0, 0, 0};
        for (int i = 0; i < 8; ++i) {
            int e4 = i * 256 + threadIdx.x;  // < 2048
            int b = e4 >> 10, rem = e4 & 1023;
            int g = rem >> 7, c4 = (rem & 127) * 4;
            *(ushort4*)&zbuf[(size_t)(b * ZBROWS + g) * 512 + c4] = z4;
        }
        return;
    }
    int t = (bid - 33) * 256 + threadIdx.x;  // ROWS*D_/4 threads exactly
    int r = t >> 7, f4 = (t & 127) * 4;
    const ushort4* p = (const ushort4*)partD;
    float4 s = {0.f, 0.f, 0.f, 0.f};
    #pragma unroll
    for (int c = 0; c < SPLITD; ++c) {
        ushort4 v = p[(size_t)c * (ROWS * D_ / 4) + t];
        s.x += __uint_as_float((unsigned)v.x << 16);
        s.y += __uint_as_float((unsigned)v.y << 16);
        s.z += __uint_as_float((unsigned)v.z << 16);
        s.w += __uint_as_float((unsigned)v.w << 16);
    }
    ((float4*)z)[t] = s;
    ushort4 zb4;
    { bf16 h;
      h = __float2bfloat16(s.x); zb4.x = *(unsigned short*)&h;
      h = __float2bfloat16(s.y); zb4.y = *(unsigned short*)&h;
      h = __float2bfloat16(s.z); zb4.z = *(unsigned short*)&h;
      h = __float2bfloat16(s.w); zb4.w = *(unsigned short*)&h; }
    int b = r >> 10, li = r & 1023;
    *(ushort4*)&zbuf[(size_t)(b * ZBROWS + 8 + li) * 512 + f4] = zb4;
}

// out = z + sum of SPLITR bf16 Stage-R partials
__global__ void reduce_out(const float* __restrict__ z, const bf16* __restrict__ partR,
                           float* __restrict__ out) {
    int t = blockIdx.x * 256 + threadIdx.x;
    if (t >= ROWS * D_ / 4) return;
    float4 s = ((const float4*)z)[t];
    const ushort4* p = (const ushort4*)partR;
    #pragma unroll
    for (int c = 0; c < SPLITR; ++c) {
        ushort4 v = p[(size_t)c * (ROWS * D_ / 4) + t];
        s.x += __uint_as_float((unsigned)v.x << 16);
        s.y += __uint_as_float((unsigned)v.y << 16);
        s.z += __uint_as_float((unsigned)v.z << 16);
        s.w += __uint_as_float((unsigned)v.w << 16);
    }
    ((float4*)out)[t] = s;
}

// ------ Stage C: parity-split conv, 128x128 blocks, 3-buf, 3 blocks/CU -----
__global__ __launch_bounds__(256, 3) void conv_misc(
    const bf16* __restrict__ W, const bf16* __restrict__ uPT,
    bf16* __restrict__ U,
    const bf16* PB, const bf16* BTT, const bf16* Myb)
{
    __shared__ bf16 sA[3][4096];
    __shared__ bf16 sB[3][4096];
    const int z = blockIdx.z;
    if (z < 3) {
        int row0 = blockIdx.x * 128, col0 = blockIdx.y * 128;
        bf16* BTTw = (bf16*)BTT; bf16* PBw = (bf16*)PB;
        if (z == 0)
            phi_body(PB, PBLD, BTT, 1024, PBw + 2 * 512, PBLD, 1024,
                     nullptr, 0, row0, col0, &sA[0][0], &sB[0][0]);
        else if (z == 1)
            phi_body(BTT + 512, 1024, Myb + 512, 1024,
                     BTTw + (size_t)512 * 1024, 1024, 512,
                     nullptr, 0, row0, col0, &sA[0][0], &sB[0][0]);
        else
            phi_body(BTT + 512, 1024, Myb, 1024,
                     BTTw + (size_t)512 * 1024 + 512, 1024, 512,
                     BTT, 1024, row0, col0, &sA[0][0], &sB[0][0]);
        return;
    }
    const int zc = z - 3;
    const int mt = 3 - blockIdx.x, dt = blockIdx.y * 128;
    const int t = zc & 3, b = (zc >> 2) & 1, k = zc >> 3;
    const int pb_ = t & 1;
    const int p = (t & 1) ^ (t >> 1);
    const int set = (t < 2) ? 0 : (t == 2 ? 1 : 2);
    const int ch = (t < 2) ? k : 16 + k;
    const int plane = b * 2 + pb_;
    const int tid = threadIdx.x, lane = tid & 63, wave = tid >> 6;
    const int wm = (wave & 1) * 64, wn = (wave >> 1) * 64;
    const int ml = lane & 15, q = lane >> 4;
    const int srow = lane >> 2, scol = (((lane & 3) ^ ((srow >> 1) & 3))) * 8;
    const int swz = ((ml >> 1) & 3);
    f32x4 acc[4][4] = {};
    const int n = (mt + 1) * 4;              // 32-K steps

    const bf16* bB0 = uPT + ((size_t)plane * 512 + dt + wave * 16       + srow) * 512 + scol;
    const bf16* bB1 = uPT + ((size_t)plane * 512 + dt + (wave + 4) * 16 + srow) * 512 + scol;
    const bf16* wbase = W + ((size_t)(set * 16 + k) * 16) * 4096;
    auto stage = [&](int s, int buf) {
        const bf16* wt = wbase + ((size_t)((mt - (s >> 2)) * 4 + (s & 3))) * 4096;
        gll16(wt + wave * 512 + lane * 8, &sA[buf][wave * 512]);
        gll16(wt + (wave + 4) * 512 + lane * 8, &sA[buf][(wave + 4) * 512]);
        gll16(bB0 + s * 32, &sB[buf][wave * 512]);
        gll16(bB1 + s * 32, &sB[buf][(wave + 4) * 512]);
    };
    auto compute = [&](int c) {
        bf16x8 af[4], bfr[4];
        #pragma unroll
        for (int i = 0; i < 4; ++i)
            af[i] = *(const bf16x8*)&sA[c][(wm + i * 16 + ml) * 32 + (q ^ swz) * 8];
        #pragma unroll
        for (int j = 0; j < 4; ++j)
            bfr[j] = *(const bf16x8*)&sB[c][(wn + j * 16 + ml) * 32 + (q ^ swz) * 8];
        #pragma unroll
        for (int i = 0; i < 4; ++i)
            #pragma unroll
            for (int j = 0; j < 4; ++j)
                acc[i][j] = __builtin_amdgcn_mfma_f32_16x16x32_bf16(af[i], bfr[j], acc[i][j], 0, 0, 0);
    };
    stage(0, 0); stage(1, 1);
    int c = 0, nb = 2;
    for (int i = 0; i < n - 1; ++i) {
        __builtin_amdgcn_s_waitcnt(WAIT_VM4);
        __builtin_amdgcn_s_barrier();
        if (i + 2 < n) stage(i + 2, nb);
        compute(c);
        c = (c == 2) ? 0 : c + 1; nb = (nb == 2) ? 0 : nb + 1;
    }
    __builtin_amdgcn_s_waitcnt(WAIT_VM0);
    __builtin_amdgcn_s_barrier();
    compute(c);

    #pragma unroll
    for (int i = 0; i < 4; ++i)
        #pragma unroll
        for (int j = 0; j < 4; ++j)
            #pragma unroll
            for (int reg = 0; reg < 4; ++reg) {
                int m = mt * 128 + wm + i * 16 + q * 4 + reg;
                int l = 2 * m + p;
                int d = dt + wn + j * 16 + ml;
                U[(size_t)(b * L_ + l) * KT + ch * 512 + d] = __float2bfloat16(acc[i][j][reg]);
            }
}

// ---- paired-barrier 128x128 K-loop body (n even): dbuf of stage PAIRS ------
// 4 LDS stages x (8KB A + 8KB B); one vmcnt(0)+s_barrier per 64-K phase.
__device__ __forceinline__ void mm128_pair(
    const bf16* Abase, int alda, const bf16* Bbase, int ldb, int n,
    bf16* o, int row0, int col0, bf16 (*sA)[4096], bf16 (*sB)[4096])
{
    const int tid = threadIdx.x, lane = tid & 63, wave = tid >> 6;
    const int wm = (wave & 1) * 64, wn = (wave >> 1) * 64;
    const int ml = lane & 15, q = lane >> 4;
    const int srow = lane >> 2, scol = (((lane & 3) ^ ((srow >> 1) & 3))) * 8;
    const int swz = ((ml >> 1) & 3);
    f32x4 acc[4][4] = {};

    const bf16* bA0 = Abase + (size_t)(wave * 16 + srow) * alda + scol;
    const bf16* bA1 = Abase + (size_t)((wave + 4) * 16 + srow) * alda + scol;
    const bf16* bB0 = Bbase + (size_t)(wave * 16 + srow) * ldb + scol;
    const bf16* bB1 = Bbase + (size_t)((wave + 4) * 16 + srow) * ldb + scol;
    auto stage = [&](int s) {
        int buf = s & 3;
        gll16(bA0 + s * 32, &sA[buf][wave * 512]);
        gll16(bA1 + s * 32, &sA[buf][(wave + 4) * 512]);
        gll16(bB0 + s * 32, &sB[buf][wave * 512]);
        gll16(bB1 + s * 32, &sB[buf][(wave + 4) * 512]);
    };
    auto compute = [&](int c) {
        bf16x8 af[4], bfr[4];
        #pragma unroll
        for (int i = 0; i < 4; ++i)
            af[i] = *(const bf16x8*)&sA[c][(wm + i * 16 + ml) * 32 + (q ^ swz) * 8];
        #pragma unroll
        for (int j = 0; j < 4; ++j)
            bfr[j] = *(const bf16x8*)&sB[c][(wn + j * 16 + ml) * 32 + (q ^ swz) * 8];
        #pragma unroll
        for (int i = 0; i < 4; ++i)
            #pragma unroll
            for (int j = 0; j < 4; ++j)
                acc[i][j] = __builtin_amdgcn_mfma_f32_16x16x32_bf16(af[i], bfr[j], acc[i][j], 0, 0, 0);
    };
    stage(0); stage(1);                       // pair 0
    const int npair = n >> 1;
    for (int p = 0; p < npair; ++p) {
        __builtin_amdgcn_s_waitcnt(WAIT_VM0); // pair p landed
        __builtin_amdgcn_s_barrier();
        if (2 * p + 2 < n) { stage(2 * p + 2); stage(2 * p + 3); } // pair p+1
        compute((2 * p) & 3);
        compute((2 * p + 1) & 3);
    }
    #pragma unroll
    for (int i = 0; i < 4; ++i)
        #pragma unroll
        for (int j = 0; j < 4; ++j)
            #pragma unroll
            for (int reg = 0; reg < 4; ++reg) {
                int r = row0 + wm + i * 16 + q * 4 + reg;
                int cc = col0 + wn + j * 16 + ml;
                o[(size_t)r * D_ + cc] = __float2bfloat16(acc[i][j][reg]);
            }
}

// Stage D: 1-D grid 544. id<32 = Phi doubling1. id>=32: xcd=id&7 owns split
// zz=xcd (+8 offsets for 8..15 unused at SPLITD=8); col quads adjacent.
__global__ __launch_bounds__(256, 2) void gemm_d(
    const bf16* __restrict__ U, const bf16* __restrict__ BT,
    bf16* __restrict__ part, const bf16* PB, const bf16* BTT)
{
    __shared__ bf16 sA[4][4096];
    __shared__ bf16 sB[4][4096];
    int id = blockIdx.x;
    if (id < 32) {                            // doubling1: [P3|P4] = [P1|P2] x BTT
        int r0_ = (id & 3) * 128, c0_ = (id >> 2) * 128;   // 4x8 tiles: 512x1024
        phi_body(PB + 512, PBLD, BTT, 1024, (bf16*)PB + 3 * 512, PBLD, 1024,
                 nullptr, 0, r0_, c0_, &sA[0][0], &sB[0][0]);
        return;
    }
    id -= 32;                                 // 512 main blocks
    const int xcd = id & 7, n_ = id >> 3;     // n_ in [0,64)
    const int zz = xcd;                       // one split per XCD
    const int row0 = (n_ >> 2) * 128, col0 = (n_ & 3) * 128;
    const int kc = KT / SPLITD;               // 2240 -> 70 steps (35 pairs)
    mm128_pair(U + (size_t)row0 * KT + (size_t)zz * kc, KT,
               BT + (size_t)col0 * KT + (size_t)zz * kc, KT,
               kc >> 5, part + (size_t)zz * ROWS * D_, row0, col0, sA, sB);
}

// Stage R: grid (16,4,6); A = guard-padded z taps in-place (tap s = zz+1).
__global__ __launch_bounds__(256, 2) void gemm_r(
    const bf16* __restrict__ zbuf, const bf16* __restrict__ BT,
    bf16* __restrict__ part)
{
    __shared__ bf16 sA[4][4096];
    __shared__ bf16 sB[4][4096];
    const int row0 = blockIdx.x * 128, col0 = blockIdx.y * 128;
    const int zz = blockIdx.z;
    const int s = 1 + zz;
    const int b = row0 >> 10, li0 = row0 & 1023;
    mm128_pair(zbuf + ((size_t)(b * ZBROWS + 8 + li0 - s)) * 512, 512,
               BT + (size_t)col0 * PBLD + (size_t)zz * 512, PBLD,
               16, part + (size_t)zz * ROWS * D_, row0, col0, sA, sB);
}

// ---------------- launch ----------------
extern "C" void kernel_launch(void* const* d_in, const int* in_sizes, int n_in,
                              void* d_out, int out_size, void* d_ws, size_t ws_size,
                              hipStream_t stream) {
    const float* u   = (const float*)d_in[0];
    const float* fil = (const float*)d_in[1];
    const float* Mu  = (const float*)d_in[2];
    const float* My  = (const float*)d_in[3];
    const float* Mp  = (const float*)d_in[4];
    const float* Mm  = (const float*)d_in[5];
    float* out = (float*)d_out;

    char* ws = (char*)d_ws;
    size_t off = 0;
    auto alloc = [&](size_t bytes) { void* p = ws + off; off = (off + bytes + 255) & ~(size_t)255; return p; };
    bf16*  U    = (bf16*) alloc((size_t)ROWS * KT * 2);        // 73.4 MB
    bf16*  BT   = (bf16*) alloc((size_t)512 * KT * 2);         // 18.4 MB
    bf16*  PB   = (bf16*) alloc((size_t)512 * PBLD * 2);       //  3.7 MB
    bf16*  BTT  = (bf16*) alloc((size_t)1024 * 1024 * 2);      //  2.1 MB
    bf16*  Myb  = (bf16*) alloc((size_t)512 * 1024 * 2);       //  1.0 MB
    float* z    = (float*)alloc((size_t)ROWS * D_ * 4);        //  4.2 MB
    bf16*  zb   = (bf16*) alloc((size_t)B_ * ZBROWS * 512 * 2);//  2.1 MB
    // overlapped region: {W + uPT} dead after conv; bf16 partD written after;
    // partD dead after k_ztaps; bf16 partR written after.
    char*  region = (char*)alloc((size_t)16 * ROWS * D_ * 2);  // 32 MB
    bf16*  W    = (bf16*)region;                               //  6.3 MB (768 tiles)
    bf16*  uPT  = (bf16*)(region + (size_t)768 * 4096 * 2);    //  2.1 MB
    bf16*  partD = (bf16*)region;                              //  8 x 2 MB
    bf16*  partR = (bf16*)region;                              //  6 x 2 MB

    // all preps (1 launch)
    prep_all<<<7872, 256, 0, stream>>>(u, fil, Mu, My, Mp, Mm,
                                       U, BT, PB, W, Myb, BTT, uPT);

    // Stage C (parity-split conv, 128x128, 3 blocks/CU) + phi_misc (z=0..2)
    conv_misc<<<dim3(4, 4, 131), 256, 0, stream>>>(W, uPT, U, PB, BTT, Myb);

    // Stage D split-K 8 (one split per XCD), paired-barrier + doubling1 (id<32)
    gemm_d<<<544, 256, 0, stream>>>(U, BT, partD, PB, BTT);

    // reduce partials -> z + guarded bf16 copy; Phi doubling2 fused (bid<32)
    k_ztaps<<<1057, 256, 0, stream>>>(partD, z, zb, PB, BTT);

    // Stage R: tap-partials, A = z taps in-place (6 splits = 1 tap each)
    gemm_r<<<dim3(16, 4, SPLITR), 256, 0, stream>>>(zb, PB + 512, partR);

    // out = z + sum partR
    reduce_out<<<(ROWS * D_ / 4 + 255) / 256, 256, 0, stream>>>(z, partR, out);
}

// Round 13
// 244.879 us; speedup vs baseline: 1.0561x; 1.0561x over previous
//
#include <hip/hip_runtime.h>
#include <hip/hip_bf16.h>

// STU forward. R13 = R11/R12 hybrid + 256x256 Stage-D tiles:
//  Stage D time is pinned to staged-LDS bytes (~25 B/cyc/CU across R7-R12).
//  staged = 2K*M*N*(1/tm+1/tn); tm=256 halves the dominant B-restage term:
//  440 MB -> 293 MB. 512-thr blocks (8 waves, wave 64x128, acc[4][8]),
//  96 KB 3-stage LDS ring, vmcnt(4) pipeline, SPLITD=14 -> exactly 256
//  blocks (224 main + 32 fused-Phi) = 1 block/CU uniform.
// conv (128x128 3-buf), gemm_r (paired 128x128), preps, ztaps as R12.
// NTAP=6, bf16 split-K partials, fused Phi chain, 6 launches, XOR swizzle.

using bf16 = __hip_bfloat16;
typedef __attribute__((ext_vector_type(8))) short bf16x8;
typedef __attribute__((ext_vector_type(4))) float f32x4;

#define B_   2
#define L_   1024
#define D_   512
#define K_   16
#define KT   17920      // 32*512 (conv channels) + 3*512 (M_u taps)
#define ROWS 2048       // B*L
#define NTAP 6          // AR taps s=1..6 (s=0 identity in fp32)
#define PBLD 3584       // PB row stride: 7 slots (s=0..6) * 512
#define SPLITD 14       // kc=1280; 224 main blocks + 32 phi = 256 = 1/CU
#define SPLITR 6        // one tap per split, K=512
#define ZBROWS 1032     // 8 guard rows + 1024 per batch

// s_waitcnt imm: [3:0] vmcnt lo, [6:4] expcnt, [11:8] lgkmcnt, [15:14] vmcnt hi
#define WAIT_VM4 0x0F74   // vmcnt<=4 (one stage = 4 loads/wave)
#define WAIT_VM0 0x0F70

__device__ __forceinline__ void gll16(const void* g, void* l) {
    __builtin_amdgcn_global_load_lds(
        (const __attribute__((address_space(1))) unsigned int*)g,
        (__attribute__((address_space(3))) unsigned int*)l, 16, 0, 0);
}

// ---------------- prep: ALL prep work in one launch ----------------
__global__ void prep_all(const float* __restrict__ u, const float* __restrict__ fil,
                         const float* __restrict__ Mu, const float* __restrict__ My,
                         const float* __restrict__ Mp, const float* __restrict__ Mm,
                         bf16* __restrict__ U, bf16* __restrict__ BT,
                         bf16* __restrict__ PB, bf16* __restrict__ W,
                         bf16* __restrict__ Myb, bf16* __restrict__ BTT,
                         bf16* __restrict__ uPT) {
    __shared__ bf16 t[64][72];
    int bid = blockIdx.x, tid = threadIdx.x;
    auto pack4 = [](float4 v) {
        ushort4 o; bf16 h;
        h = __float2bfloat16(v.x); o.x = *(unsigned short*)&h;
        h = __float2bfloat16(v.y); o.y = *(unsigned short*)&h;
        h = __float2bfloat16(v.z); o.z = *(unsigned short*)&h;
        h = __float2bfloat16(v.w); o.w = *(unsigned short*)&h;
        return o;
    };
    if (bid < 3072) {                        // U taps
        int e4 = bid * 256 + tid;
        int r = e4 / 384, rem = e4 % 384;
        int tt = rem >> 7, f = (rem & 127) * 4;
        int b = r >> 10, l = r & 1023;
        float4 v = {0.f, 0.f, 0.f, 0.f};
        if (l >= tt) v = *(const float4*)&u[((size_t)b * L_ + l - tt) * D_ + f];
        *(ushort4*)&U[(size_t)r * KT + 16384 + tt * 512 + f] = pack4(v);
    } else if (bid < 3840) {                 // BT taps
        int e4 = (bid - 3072) * 256 + tid;
        int o = e4 / 384, tf4 = (e4 % 384) * 4;
        float4 v = *(const float4*)&Mu[(size_t)o * 1536 + tf4];
        *(ushort4*)&BT[(size_t)o * KT + 16384 + tf4] = pack4(v);
    } else if (bid < 4352) {                 // PB: P0=I, P1=M_y[:,0,:]
        int e4 = (bid - 3840) * 256 + tid;
        int n = e4 >> 8, c4 = (e4 & 255) * 4;
        float4 v;
        if (c4 < 512) {
            v.x = (n == c4) ? 1.f : 0.f;     v.y = (n == c4 + 1) ? 1.f : 0.f;
            v.z = (n == c4 + 2) ? 1.f : 0.f; v.w = (n == c4 + 3) ? 1.f : 0.f;
        } else v = *(const float4*)&My[(size_t)n * 1024 + (c4 - 512)];
        *(ushort4*)&PB[(size_t)n * PBLD + c4] = pack4(v);
    } else if (bid < 5120) {                 // Toeplitz W tiles (3 sets), pre-swizzled
        int tile = bid - 4352;
        int set = tile >> 8, rem = tile & 255;
        int k = rem >> 4, g = (rem >> 2) & 3, kb = rem & 3;
        for (int idx = tid; idx < 4096; idx += 256) {
            int i = idx >> 5, jp = idx & 31;
            int j = ((jp >> 3) ^ ((i >> 1) & 3)) * 8 + (jp & 7);
            int x = g * 128 + i - kb * 32 - j - (set == 2 ? 1 : 0);
            float v = 0.f;
            if (x >= 0) {
                int row = (set == 0) ? 2 * x : 2 * x + 1;
                v = fil[row * K_ + k];
            }
            W[(size_t)tile * 4096 + idx] = __float2bfloat16(v);
        }
    } else if (bid < 5632) {                 // Myb = bf16(My)
        int e4 = (bid - 5120) * 256 + tid;
        float4 v = *(const float4*)&My[(size_t)e4 * 4];
        *(ushort4*)&Myb[(size_t)e4 * 4] = pack4(v);
    } else {                                 // ---- transpose sections ----
        int tt = bid - 5632;                 // 2240 = 35 z * 64 (x,y)
        int zb = tt >> 6, rem = tt & 63;
        int bx = rem & 7, by = rem >> 3;
        int col = tid & 63, r0 = (tid >> 6) * 16;
        if (zb < 32) {                       // BT[o][c*512+d] = (Mp +/- Mm)[k][d][o]
            int dt = bx * 64, ot = by * 64, c = zb;
            int k = c & 15;
            const float* sp = Mp + (size_t)k * D_ * D_;
            const float* sm = Mm + (size_t)k * D_ * D_;
            float sg = (c < 16) ? 1.f : -1.f;
            for (int i = 0; i < 16; ++i) {
                size_t o_ = (size_t)(dt + r0 + i) * D_ + ot + col;
                t[r0 + i][col] = __float2bfloat16(sp[o_] + sg * sm[o_]);
            }
            __syncthreads();
            for (int i = 0; i < 16; ++i)
                BT[(size_t)(ot + r0 + i) * KT + c * D_ + dt + col] = t[col][r0 + i];
        } else if (zb < 34) {                // BTT[f][h*512+d] = M_y[d][1-h][f]
            int h = zb - 32;
            int dt = bx * 64, ft = by * 64;
            for (int i = 0; i < 16; ++i)
                t[r0 + i][col] = __float2bfloat16(My[(size_t)(dt + r0 + i) * 1024 + (1 - h) * 512 + ft + col]);
            __syncthreads();
            for (int i = 0; i < 16; ++i)
                BTT[(size_t)(ft + r0 + i) * 1024 + h * 512 + dt + col] = t[col][r0 + i];
        } else {                             // uPT[b][p][d][m'] = u[b][2m'+p][d]
            for (int it = 0; it < 4; ++it) {
                int b = it >> 1, p = it & 1;
                int mt = bx * 64, dt = by * 64;
                __syncthreads();
                for (int i = 0; i < 16; ++i)
                    t[r0 + i][col] = __float2bfloat16(u[((size_t)b * L_ + 2 * (mt + r0 + i) + p) * D_ + dt + col]);
                __syncthreads();
                for (int i = 0; i < 16; ++i)
                    uPT[((size_t)it * 512 + dt + r0 + i) * 512 + mt + col] = t[col][r0 + i];
            }
        }
    }
}

// ---- shared body for small bf16-out GEMMs (waves 0-3; caller LDS) ----
__device__ __forceinline__ void phi_body(
    const bf16* A, int lda, const bf16* BT, int ldb,
    bf16* out, int ldo, int klen, const bf16* add, int lad,
    int row0, int col0, bf16* sA, bf16* sB)
{
    const int tid = threadIdx.x, lane = tid & 63, wave = tid >> 6;
    const int wm = (wave & 1) * 64, wn = (wave >> 1) * 64;
    const int ml = lane & 15, q = lane >> 4;
    const int srow = lane >> 2, scol = (((lane & 3) ^ ((srow >> 1) & 3))) * 8;
    const int swz = ((ml >> 1) & 3);
    f32x4 acc[4][4] = {};

    for (int k = 0; k < klen; k += 32) {
        __syncthreads();
        #pragma unroll
        for (int repi = 0; repi < 2; ++repi) {
            int a = wave + repi * 4;
            gll16(A  + (size_t)(row0 + a * 16 + srow) * lda + k + scol, &sA[a * 512]);
            gll16(BT + (size_t)(col0 + a * 16 + srow) * ldb + k + scol, &sB[a * 512]);
        }
        __syncthreads();
        bf16x8 af[4], bfr[4];
        #pragma unroll
        for (int i = 0; i < 4; ++i)
            af[i] = *(const bf16x8*)&sA[(wm + i * 16 + ml) * 32 + (q ^ swz) * 8];
        #pragma unroll
        for (int j = 0; j < 4; ++j)
            bfr[j] = *(const bf16x8*)&sB[(wn + j * 16 + ml) * 32 + (q ^ swz) * 8];
        #pragma unroll
        for (int i = 0; i < 4; ++i)
            #pragma unroll
            for (int j = 0; j < 4; ++j)
                acc[i][j] = __builtin_amdgcn_mfma_f32_16x16x32_bf16(af[i], bfr[j], acc[i][j], 0, 0, 0);
    }
    #pragma unroll
    for (int i = 0; i < 4; ++i)
        #pragma unroll
        for (int j = 0; j < 4; ++j)
            #pragma unroll
            for (int reg = 0; reg < 4; ++reg) {
                int r = row0 + wm + i * 16 + q * 4 + reg;
                int cc = col0 + wn + j * 16 + ml;
                float v = acc[i][j][reg];
                if (add) v += __bfloat162float(add[(size_t)r * lad + cc]);
                out[(size_t)r * ldo + cc] = __float2bfloat16(v);
            }
}

// sum 14 bf16 Stage-D partials -> z (fp32) + guard-padded bf16 copy zb
// bid<32: fused Phi doubling2 [P5|P6] = [P3|P4] x BTT (dispatched first)
// bid==32: zero the guard rows of zb
__global__ void k_ztaps(const bf16* __restrict__ partD, float* __restrict__ z,
                        bf16* __restrict__ zbuf, bf16* PB, const bf16* BTT) {
    __shared__ bf16 sA[4096];
    __shared__ bf16 sB[4096];
    int bid = blockIdx.x;
    if (bid < 32) {
        int row0 = (bid & 3) * 128, col0 = (bid >> 2) * 128;   // 4 x 8 tiles: 512x1024
        phi_body(PB + 3 * 512, PBLD, BTT, 1024, PB + 5 * 512, PBLD, 1024,
                 nullptr, 0, row0, col0, sA, sB);
        return;
    }
    if (bid == 32) {                         // zero 2x8 guard rows
        ushort4 z4 = {0, 0, 0, 0};
        for (int i = 0; i < 8; ++i) {
            int e4 = i * 256 + threadIdx.x;  // < 2048
            int b = e4 >> 10, rem = e4 & 1023;
            int g = rem >> 7, c4 = (rem & 127) * 4;
            *(ushort4*)&zbuf[(size_t)(b * ZBROWS + g) * 512 + c4] = z4;
        }
        return;
    }
    int t = (bid - 33) * 256 + threadIdx.x;  // ROWS*D_/4 threads exactly
    int r = t >> 7, f4 = (t & 127) * 4;
    const ushort4* p = (const ushort4*)partD;
    float4 s = {0.f, 0.f, 0.f, 0.f};
    #pragma unroll
    for (int c = 0; c < SPLITD; ++c) {
        ushort4 v = p[(size_t)c * (ROWS * D_ / 4) + t];
        s.x += __uint_as_float((unsigned)v.x << 16);
        s.y += __uint_as_float((unsigned)v.y << 16);
        s.z += __uint_as_float((unsigned)v.z << 16);
        s.w += __uint_as_float((unsigned)v.w << 16);
    }
    ((float4*)z)[t] = s;
    ushort4 zb4;
    { bf16 h;
      h = __float2bfloat16(s.x); zb4.x = *(unsigned short*)&h;
      h = __float2bfloat16(s.y); zb4.y = *(unsigned short*)&h;
      h = __float2bfloat16(s.z); zb4.z = *(unsigned short*)&h;
      h = __float2bfloat16(s.w); zb4.w = *(unsigned short*)&h; }
    int b = r >> 10, li = r & 1023;
    *(ushort4*)&zbuf[(size_t)(b * ZBROWS + 8 + li) * 512 + f4] = zb4;
}

// out = z + sum of SPLITR bf16 Stage-R partials
__global__ void reduce_out(const float* __restrict__ z, const bf16* __restrict__ partR,
                           float* __restrict__ out) {
    int t = blockIdx.x * 256 + threadIdx.x;
    if (t >= ROWS * D_ / 4) return;
    float4 s = ((const float4*)z)[t];
    const ushort4* p = (const ushort4*)partR;
    #pragma unroll
    for (int c = 0; c < SPLITR; ++c) {
        ushort4 v = p[(size_t)c * (ROWS * D_ / 4) + t];
        s.x += __uint_as_float((unsigned)v.x << 16);
        s.y += __uint_as_float((unsigned)v.y << 16);
        s.z += __uint_as_float((unsigned)v.z << 16);
        s.w += __uint_as_float((unsigned)v.w << 16);
    }
    ((float4*)out)[t] = s;
}

// ------ Stage C: parity-split conv, 128x128 blocks, 3-buf, 3 blocks/CU -----
__global__ __launch_bounds__(256, 3) void conv_misc(
    const bf16* __restrict__ W, const bf16* __restrict__ uPT,
    bf16* __restrict__ U,
    const bf16* PB, const bf16* BTT, const bf16* Myb)
{
    __shared__ bf16 sA[3][4096];
    __shared__ bf16 sB[3][4096];
    const int z = blockIdx.z;
    if (z < 3) {
        int row0 = blockIdx.x * 128, col0 = blockIdx.y * 128;
        bf16* BTTw = (bf16*)BTT; bf16* PBw = (bf16*)PB;
        if (z == 0)
            phi_body(PB, PBLD, BTT, 1024, PBw + 2 * 512, PBLD, 1024,
                     nullptr, 0, row0, col0, &sA[0][0], &sB[0][0]);
        else if (z == 1)
            phi_body(BTT + 512, 1024, Myb + 512, 1024,
                     BTTw + (size_t)512 * 1024, 1024, 512,
                     nullptr, 0, row0, col0, &sA[0][0], &sB[0][0]);
        else
            phi_body(BTT + 512, 1024, Myb, 1024,
                     BTTw + (size_t)512 * 1024 + 512, 1024, 512,
                     BTT, 1024, row0, col0, &sA[0][0], &sB[0][0]);
        return;
    }
    const int zc = z - 3;
    const int mt = 3 - blockIdx.x, dt = blockIdx.y * 128;
    const int t = zc & 3, b = (zc >> 2) & 1, k = zc >> 3;
    const int pb_ = t & 1;
    const int p = (t & 1) ^ (t >> 1);
    const int set = (t < 2) ? 0 : (t == 2 ? 1 : 2);
    const int ch = (t < 2) ? k : 16 + k;
    const int plane = b * 2 + pb_;
    const int tid = threadIdx.x, lane = tid & 63, wave = tid >> 6;
    const int wm = (wave & 1) * 64, wn = (wave >> 1) * 64;
    const int ml = lane & 15, q = lane >> 4;
    const int srow = lane >> 2, scol = (((lane & 3) ^ ((srow >> 1) & 3))) * 8;
    const int swz = ((ml >> 1) & 3);
    f32x4 acc[4][4] = {};
    const int n = (mt + 1) * 4;              // 32-K steps

    const bf16* bB0 = uPT + ((size_t)plane * 512 + dt + wave * 16       + srow) * 512 + scol;
    const bf16* bB1 = uPT + ((size_t)plane * 512 + dt + (wave + 4) * 16 + srow) * 512 + scol;
    const bf16* wbase = W + ((size_t)(set * 16 + k) * 16) * 4096;
    auto stage = [&](int s, int buf) {
        const bf16* wt = wbase + ((size_t)((mt - (s >> 2)) * 4 + (s & 3))) * 4096;
        gll16(wt + wave * 512 + lane * 8, &sA[buf][wave * 512]);
        gll16(wt + (wave + 4) * 512 + lane * 8, &sA[buf][(wave + 4) * 512]);
        gll16(bB0 + s * 32, &sB[buf][wave * 512]);
        gll16(bB1 + s * 32, &sB[buf][(wave + 4) * 512]);
    };
    auto compute = [&](int c) {
        bf16x8 af[4], bfr[4];
        #pragma unroll
        for (int i = 0; i < 4; ++i)
            af[i] = *(const bf16x8*)&sA[c][(wm + i * 16 + ml) * 32 + (q ^ swz) * 8];
        #pragma unroll
        for (int j = 0; j < 4; ++j)
            bfr[j] = *(const bf16x8*)&sB[c][(wn + j * 16 + ml) * 32 + (q ^ swz) * 8];
        #pragma unroll
        for (int i = 0; i < 4; ++i)
            #pragma unroll
            for (int j = 0; j < 4; ++j)
                acc[i][j] = __builtin_amdgcn_mfma_f32_16x16x32_bf16(af[i], bfr[j], acc[i][j], 0, 0, 0);
    };
    stage(0, 0); stage(1, 1);
    int c = 0, nb = 2;
    for (int i = 0; i < n - 1; ++i) {
        __builtin_amdgcn_s_waitcnt(WAIT_VM4);
        __builtin_amdgcn_s_barrier();
        if (i + 2 < n) stage(i + 2, nb);
        compute(c);
        c = (c == 2) ? 0 : c + 1; nb = (nb == 2) ? 0 : nb + 1;
    }
    __builtin_amdgcn_s_waitcnt(WAIT_VM0);
    __builtin_amdgcn_s_barrier();
    compute(c);

    #pragma unroll
    for (int i = 0; i < 4; ++i)
        #pragma unroll
        for (int j = 0; j < 4; ++j)
            #pragma unroll
            for (int reg = 0; reg < 4; ++reg) {
                int m = mt * 128 + wm + i * 16 + q * 4 + reg;
                int l = 2 * m + p;
                int d = dt + wn + j * 16 + ml;
                U[(size_t)(b * L_ + l) * KT + ch * 512 + d] = __float2bfloat16(acc[i][j][reg]);
            }
}

// ---- Stage D: 256x256 tiles, 512 threads (8 waves, wave 64x128) ------------
// grid 256 (1-D, 1 block/CU). id<32: Phi doubling1 (waves 0-3 active).
// id>=32: id-=32; zz = id>>4 (14 splits); n_=id&15: row0=(n_>>1)*256,
// col0=(n_&1)*256. 3-stage 96 KB LDS ring, 4 gll/wave/stage, vmcnt(4).
__global__ __launch_bounds__(512, 1) void gemm_d(
    const bf16* __restrict__ U, const bf16* __restrict__ BT,
    bf16* __restrict__ part, const bf16* PB, const bf16* BTT)
{
    __shared__ bf16 sA[3][8192];
    __shared__ bf16 sB[3][8192];
    int id = blockIdx.x;
    const int tid = threadIdx.x, lane = tid & 63, wave = tid >> 6;
    if (id < 32) {                            // doubling1: [P3|P4] = [P1|P2] x BTT
        if (wave >= 4) {                      // barrier-matched idle loop
            for (int i = 0; i < 64; ++i) __syncthreads();
            return;
        }
        int r0_ = (id & 3) * 128, c0_ = (id >> 2) * 128;   // 4x8 tiles: 512x1024
        phi_body(PB + 512, PBLD, BTT, 1024, (bf16*)PB + 3 * 512, PBLD, 1024,
                 nullptr, 0, r0_, c0_, &sA[0][0], &sB[0][0]);
        return;
    }
    id -= 32;                                 // 224 main blocks
    const int zz = id >> 4;                   // 14 splits
    const int n_ = id & 15;
    const int row0 = (n_ >> 1) * 256, col0 = (n_ & 1) * 256;
    const int kc = KT / SPLITD;               // 1280 -> 40 steps
    const int k0 = zz * kc;
    const int n = kc >> 5;

    const int wm = (wave & 3) * 64, wn = (wave >> 2) * 128;
    const int ml = lane & 15, q = lane >> 4;
    const int srow = lane >> 2, scol = (((lane & 3) ^ ((srow >> 1) & 3))) * 8;
    const int swz = ((ml >> 1) & 3);
    f32x4 acc[4][8] = {};

    const int a0 = 2 * wave, a1 = 2 * wave + 1;   // 16 slots each for A and B
    const bf16* bA0 = U  + (size_t)(row0 + a0 * 16 + srow) * KT + k0 + scol;
    const bf16* bA1 = U  + (size_t)(row0 + a1 * 16 + srow) * KT + k0 + scol;
    const bf16* bB0 = BT + (size_t)(col0 + a0 * 16 + srow) * KT + k0 + scol;
    const bf16* bB1 = BT + (size_t)(col0 + a1 * 16 + srow) * KT + k0 + scol;
    auto stage = [&](int s, int buf) {
        gll16(bA0 + s * 32, &sA[buf][a0 * 512]);
        gll16(bA1 + s * 32, &sA[buf][a1 * 512]);
        gll16(bB0 + s * 32, &sB[buf][a0 * 512]);
        gll16(bB1 + s * 32, &sB[buf][a1 * 512]);
    };
    auto compute = [&](int c) {
        bf16x8 af[4], bfr[8];
        #pragma unroll
        for (int i = 0; i < 4; ++i)
            af[i] = *(const bf16x8*)&sA[c][(wm + i * 16 + ml) * 32 + (q ^ swz) * 8];
        #pragma unroll
        for (int j = 0; j < 8; ++j)
            bfr[j] = *(const bf16x8*)&sB[c][(wn + j * 16 + ml) * 32 + (q ^ swz) * 8];
        #pragma unroll
        for (int i = 0; i < 4; ++i)
            #pragma unroll
            for (int j = 0; j < 8; ++j)
                acc[i][j] = __builtin_amdgcn_mfma_f32_16x16x32_bf16(af[i], bfr[j], acc[i][j], 0, 0, 0);
    };
    stage(0, 0); stage(1, 1);
    int c = 0, nb = 2;
    for (int i = 0; i < n - 1; ++i) {
        __builtin_amdgcn_s_waitcnt(WAIT_VM4);
        __builtin_amdgcn_s_barrier();
        if (i + 2 < n) stage(i + 2, nb);
        compute(c);
        c = (c == 2) ? 0 : c + 1; nb = (nb == 2) ? 0 : nb + 1;
    }
    __builtin_amdgcn_s_waitcnt(WAIT_VM0);
    __builtin_amdgcn_s_barrier();
    compute(c);

    bf16* o = part + (size_t)zz * ROWS * D_;
    #pragma unroll
    for (int i = 0; i < 4; ++i)
        #pragma unroll
        for (int j = 0; j < 8; ++j)
            #pragma unroll
            for (int reg = 0; reg < 4; ++reg) {
                int r = row0 + wm + i * 16 + q * 4 + reg;
                int cc = col0 + wn + j * 16 + ml;
                o[(size_t)r * D_ + cc] = __float2bfloat16(acc[i][j][reg]);
            }
}

// ---- paired-barrier 128x128 K-loop body (Stage R, n even) ------------------
__device__ __forceinline__ void mm128_pair(
    const bf16* Abase, int alda, const bf16* Bbase, int ldb, int n,
    bf16* o, int row0, int col0, bf16 (*sA)[4096], bf16 (*sB)[4096])
{
    const int tid = threadIdx.x, lane = tid & 63, wave = tid >> 6;
    const int wm = (wave & 1) * 64, wn = (wave >> 1) * 64;
    const int ml = lane & 15, q = lane >> 4;
    const int srow = lane >> 2, scol = (((lane & 3) ^ ((srow >> 1) & 3))) * 8;
    const int swz = ((ml >> 1) & 3);
    f32x4 acc[4][4] = {};

    const bf16* bA0 = Abase + (size_t)(wave * 16 + srow) * alda + scol;
    const bf16* bA1 = Abase + (size_t)((wave + 4) * 16 + srow) * alda + scol;
    const bf16* bB0 = Bbase + (size_t)(wave * 16 + srow) * ldb + scol;
    const bf16* bB1 = Bbase + (size_t)((wave + 4) * 16 + srow) * ldb + scol;
    auto stage = [&](int s) {
        int buf = s & 3;
        gll16(bA0 + s * 32, &sA[buf][wave * 512]);
        gll16(bA1 + s * 32, &sA[buf][(wave + 4) * 512]);
        gll16(bB0 + s * 32, &sB[buf][wave * 512]);
        gll16(bB1 + s * 32, &sB[buf][(wave + 4) * 512]);
    };
    auto compute = [&](int c) {
        bf16x8 af[4], bfr[4];
        #pragma unroll
        for (int i = 0; i < 4; ++i)
            af[i] = *(const bf16x8*)&sA[c][(wm + i * 16 + ml) * 32 + (q ^ swz) * 8];
        #pragma unroll
        for (int j = 0; j < 4; ++j)
            bfr[j] = *(const bf16x8*)&sB[c][(wn + j * 16 + ml) * 32 + (q ^ swz) * 8];
        #pragma unroll
        for (int i = 0; i < 4; ++i)
            #pragma unroll
            for (int j = 0; j < 4; ++j)
                acc[i][j] = __builtin_amdgcn_mfma_f32_16x16x32_bf16(af[i], bfr[j], acc[i][j], 0, 0, 0);
    };
    stage(0); stage(1);                       // pair 0
    const int npair = n >> 1;
    for (int p = 0; p < npair; ++p) {
        __builtin_amdgcn_s_waitcnt(WAIT_VM0); // pair p landed
        __builtin_amdgcn_s_barrier();
        if (2 * p + 2 < n) { stage(2 * p + 2); stage(2 * p + 3); } // pair p+1
        compute((2 * p) & 3);
        compute((2 * p + 1) & 3);
    }
    #pragma unroll
    for (int i = 0; i < 4; ++i)
        #pragma unroll
        for (int j = 0; j < 4; ++j)
            #pragma unroll
            for (int reg = 0; reg < 4; ++reg) {
                int r = row0 + wm + i * 16 + q * 4 + reg;
                int cc = col0 + wn + j * 16 + ml;
                o[(size_t)r * D_ + cc] = __float2bfloat16(acc[i][j][reg]);
            }
}

// Stage R: grid (16,4,6); A = guard-padded z taps in-place (tap s = zz+1).
__global__ __launch_bounds__(256, 2) void gemm_r(
    const bf16* __restrict__ zbuf, const bf16* __restrict__ BT,
    bf16* __restrict__ part)
{
    __shared__ bf16 sA[4][4096];
    __shared__ bf16 sB[4][4096];
    const int row0 = blockIdx.x * 128, col0 = blockIdx.y * 128;
    const int zz = blockIdx.z;
    const int s = 1 + zz;
    const int b = row0 >> 10, li0 = row0 & 1023;
    mm128_pair(zbuf + ((size_t)(b * ZBROWS + 8 + li0 - s)) * 512, 512,
               BT + (size_t)col0 * PBLD + (size_t)zz * 512, PBLD,
               16, part + (size_t)zz * ROWS * D_, row0, col0, sA, sB);
}

// ---------------- launch ----------------
extern "C" void kernel_launch(void* const* d_in, const int* in_sizes, int n_in,
                              void* d_out, int out_size, void* d_ws, size_t ws_size,
                              hipStream_t stream) {
    const float* u   = (const float*)d_in[0];
    const float* fil = (const float*)d_in[1];
    const float* Mu  = (const float*)d_in[2];
    const float* My  = (const float*)d_in[3];
    const float* Mp  = (const float*)d_in[4];
    const float* Mm  = (const float*)d_in[5];
    float* out = (float*)d_out;

    char* ws = (char*)d_ws;
    size_t off = 0;
    auto alloc = [&](size_t bytes) { void* p = ws + off; off = (off + bytes + 255) & ~(size_t)255; return p; };
    bf16*  U    = (bf16*) alloc((size_t)ROWS * KT * 2);        // 73.4 MB
    bf16*  BT   = (bf16*) alloc((size_t)512 * KT * 2);         // 18.4 MB
    bf16*  PB   = (bf16*) alloc((size_t)512 * PBLD * 2);       //  3.7 MB
    bf16*  BTT  = (bf16*) alloc((size_t)1024 * 1024 * 2);      //  2.1 MB
    bf16*  Myb  = (bf16*) alloc((size_t)512 * 1024 * 2);       //  1.0 MB
    float* z    = (float*)alloc((size_t)ROWS * D_ * 4);        //  4.2 MB
    bf16*  zb   = (bf16*) alloc((size_t)B_ * ZBROWS * 512 * 2);//  2.1 MB
    // overlapped region: {W + uPT} dead after conv; bf16 partD written after;
    // partD dead after k_ztaps; bf16 partR written after.
    char*  region = (char*)alloc((size_t)16 * ROWS * D_ * 2);  // 32 MB
    bf16*  W    = (bf16*)region;                               //  6.3 MB (768 tiles)
    bf16*  uPT  = (bf16*)(region + (size_t)768 * 4096 * 2);    //  2.1 MB
    bf16*  partD = (bf16*)region;                              // 14 x 2 MB
    bf16*  partR = (bf16*)region;                              //  6 x 2 MB

    // all preps (1 launch)
    prep_all<<<7872, 256, 0, stream>>>(u, fil, Mu, My, Mp, Mm,
                                       U, BT, PB, W, Myb, BTT, uPT);

    // Stage C (parity-split conv, 128x128, 3 blocks/CU) + phi_misc (z=0..2)
    conv_misc<<<dim3(4, 4, 131), 256, 0, stream>>>(W, uPT, U, PB, BTT, Myb);

    // Stage D: 256x256 tiles, split-K 14, 256 blocks = 1/CU + doubling1 (id<32)
    gemm_d<<<256, 512, 0, stream>>>(U, BT, partD, PB, BTT);

    // reduce partials -> z + guarded bf16 copy; Phi doubling2 fused (bid<32)
    k_ztaps<<<1057, 256, 0, stream>>>(partD, z, zb, PB, BTT);

    // Stage R: tap-partials, A = z taps in-place (6 splits = 1 tap each)
    gemm_r<<<dim3(16, 4, SPLITR), 256, 0, stream>>>(zb, PB + 512, partR);

    // out = z + sum partR
    reduce_out<<<(ROWS * D_ / 4 + 255) / 256, 256, 0, stream>>>(z, partR, out);
}